// Round 5
// baseline (19.604 us; speedup 1.0000x reference)
//
#include <hip/hip_runtime.h>

// out[b,n,d] = (x@Wq+bq)[b,n,d] * kv[b,d],  kv[b,d] = sum_m ((x@Wk+bk)*(x@Wv+bv))[b,m,d]
// B=4, N=1024, D=128, fp32.
//
// R5: register-blocked LDS GEMM. R4 was LDS-INSTRUCTION-bound (13 ds_read per
// 48 v_fma). Now each lane owns 4 rows x 4 cols x 3 mats with a 4-way k-split
// across the wave: per 16-k supergroup 16 ds_read_b128 feed 192 v_fma
// (VALU:LDS ~ 4.8:1) -> VALU-bound.
//  - block 256 thr (4 waves) = 64 rows x 16 cols; wave = 64 rows x 4 cols.
//    lane = (rq 0..15: rows 4rq..4rq+3, ks 0..3: k-slice 16g+4ks..+3).
//  - LDS: x tile 64x128 (32 KB, XOR-swizzled chunks) + W slab 3x128x16
//    (24 KB) = 56 KB -> 2 blocks/CU, VGPR cap 256 (no spill).
//  - k-split reduced with shfl_xor(16,32); q row picked by cndmask select
//    (static indexing only -> no scratch).
//  - grid 512 = cg(8, high bits) x bt(64): same-tile siblings share XCD.

#define BB 4
#define NN 1024
#define DD 128
#define RT 64              // rows per block tile
#define NT 16              // rowtiles per batch
#define NBT (BB * NT)      // 64 (b,t) tiles

static __device__ __forceinline__ void fma4(float4& a, float s, float4 m) {
    a.x = fmaf(s, m.x, a.x);
    a.y = fmaf(s, m.y, a.y);
    a.z = fmaf(s, m.z, a.z);
    a.w = fmaf(s, m.w, a.w);
}

__global__ __launch_bounds__(256, 2) void proj_kernel(
    const float* __restrict__ x,
    const float* __restrict__ Wq, const float* __restrict__ bq,
    const float* __restrict__ Wk, const float* __restrict__ bk,
    const float* __restrict__ Wv, const float* __restrict__ bv,
    float* __restrict__ qout, float* __restrict__ partials)
{
    __shared__ float xs[RT * DD];        // 32 KB, chunk ^= (row&7)
    __shared__ float wt[3][DD][16];      // 24 KB: [mat][k][col-in-slab]
    const int bid = blockIdx.x;          // 512 = cg(8) x bt(64)
    const int bt  = bid & (NBT - 1);
    const int cg  = bid >> 6;            // 0..7 -> float4-cols cg*4 .. cg*4+3
    const int b   = bt >> 4;
    const int t   = bt & (NT - 1);
    const int tid = threadIdx.x;

    // ---- stage W slab: 3 x 128k x 4 float4-cols = 1536 float4s ----
    {
        const float4* Wsrc[3] = {
            reinterpret_cast<const float4*>(Wq),
            reinterpret_cast<const float4*>(Wk),
            reinterpret_cast<const float4*>(Wv)};
#pragma unroll
        for (int j = 0; j < 6; ++j) {
            const int idx = tid + j * 256;        // 0..1535
            const int m   = idx >> 9;
            const int rem = idx & 511;
            const int k   = rem >> 2, c4 = rem & 3;
            const float4 v = Wsrc[m][k * 32 + (cg << 2) + c4];
            *reinterpret_cast<float4*>(&wt[m][k][c4 << 2]) = v;
        }
    }
    // ---- stage x tile [64 rows][32 chunks], chunk ^= (row&7) ----
    {
        const float4* src = reinterpret_cast<const float4*>(
            x + ((size_t)b * NN + (size_t)t * RT) * DD);
#pragma unroll
        for (int j = 0; j < 8; ++j) {
            const int idx = tid + j * 256;        // 0..2047, coalesced
            const float4 v = src[idx];
            const int r = idx >> 5, c = idx & 31;
            *reinterpret_cast<float4*>(&xs[r * DD + ((c ^ (r & 7)) << 2)]) = v;
        }
    }
    __syncthreads();

    const int lane = tid & 63;
    const int w    = tid >> 6;            // wave 0..3
    const int rq   = lane & 15;           // row quad: rows 4rq..4rq+3
    const int ks   = lane >> 4;           // k-slice 0..3
    const int cw   = (cg << 2) + w;       // global float4-col 0..31 (uniform)

    float4 qa0 = {0,0,0,0}, qa1 = {0,0,0,0}, qa2 = {0,0,0,0}, qa3 = {0,0,0,0};
    float4 ka0 = {0,0,0,0}, ka1 = {0,0,0,0}, ka2 = {0,0,0,0}, ka3 = {0,0,0,0};
    float4 va0 = {0,0,0,0}, va1 = {0,0,0,0}, va2 = {0,0,0,0}, va3 = {0,0,0,0};

    const int r0 = rq << 2;
    const int w4 = w << 2;

#define XLD(i, g) (*reinterpret_cast<const float4*>( \
        &xs[(r0 + i) * DD + ((((g << 2) + ks) ^ ((r0 + i) & 7)) << 2)]))
#define WLD(m, g, j) (*reinterpret_cast<const float4*>( \
        &wt[m][(g << 4) + (ks << 2) + j][w4]))

#pragma unroll
    for (int g = 0; g < 8; ++g) {
        const float4 x0 = XLD(0, g);
        const float4 x1 = XLD(1, g);
        const float4 x2 = XLD(2, g);
        const float4 x3 = XLD(3, g);
#pragma unroll
        for (int j = 0; j < 4; ++j) {
            const float4 wq4 = WLD(0, g, j);
            const float4 wk4 = WLD(1, g, j);
            const float4 wv4 = WLD(2, g, j);
            const float xj0 = j == 0 ? x0.x : j == 1 ? x0.y : j == 2 ? x0.z : x0.w;
            const float xj1 = j == 0 ? x1.x : j == 1 ? x1.y : j == 2 ? x1.z : x1.w;
            const float xj2 = j == 0 ? x2.x : j == 1 ? x2.y : j == 2 ? x2.z : x2.w;
            const float xj3 = j == 0 ? x3.x : j == 1 ? x3.y : j == 2 ? x3.z : x3.w;
            fma4(qa0, xj0, wq4); fma4(ka0, xj0, wk4); fma4(va0, xj0, wv4);
            fma4(qa1, xj1, wq4); fma4(ka1, xj1, wk4); fma4(va1, xj1, wv4);
            fma4(qa2, xj2, wq4); fma4(ka2, xj2, wk4); fma4(va2, xj2, wv4);
            fma4(qa3, xj3, wq4); fma4(ka3, xj3, wk4); fma4(va3, xj3, wv4);
        }
    }
#undef XLD
#undef WLD

    // ---- combine the 4 k-slices (xor over ks bits: lanes 16,32) ----
#define RED4(a) \
    a.x += __shfl_xor(a.x, 16); a.y += __shfl_xor(a.y, 16); \
    a.z += __shfl_xor(a.z, 16); a.w += __shfl_xor(a.w, 16); \
    a.x += __shfl_xor(a.x, 32); a.y += __shfl_xor(a.y, 32); \
    a.z += __shfl_xor(a.z, 32); a.w += __shfl_xor(a.w, 32);
    RED4(qa0) RED4(qa1) RED4(qa2) RED4(qa3)
    RED4(ka0) RED4(ka1) RED4(ka2) RED4(ka3)
    RED4(va0) RED4(va1) RED4(va2) RED4(va3)
#undef RED4

    const float4 bq4 = reinterpret_cast<const float4*>(bq)[cw];
    const float4 bk4 = reinterpret_cast<const float4*>(bk)[cw];
    const float4 bv4 = reinterpret_cast<const float4*>(bv)[cw];

    // ---- q write: lane (rq,ks) writes row 4rq+ks (cndmask select) ----
    {
        const float4 qlo = ks == 0 ? qa0 : qa1;
        const float4 qhi = ks == 2 ? qa2 : qa3;
        const float4 qs  = ks < 2 ? qlo : qhi;
        float4 qo;
        qo.x = qs.x + bq4.x; qo.y = qs.y + bq4.y;
        qo.z = qs.z + bq4.z; qo.w = qs.w + bq4.w;
        reinterpret_cast<float4*>(qout)[
            ((size_t)b * NN + (size_t)t * RT + r0 + ks) * 32 + cw] = qo;
    }

    // ---- kv partial: sum (k+bk)*(v+bv) over this lane's 4 rows, then
    //      butterfly over the 16 row-quads (all ks groups identical) ----
    float4 p;
    p.x = (ka0.x+bk4.x)*(va0.x+bv4.x) + (ka1.x+bk4.x)*(va1.x+bv4.x)
        + (ka2.x+bk4.x)*(va2.x+bv4.x) + (ka3.x+bk4.x)*(va3.x+bv4.x);
    p.y = (ka0.y+bk4.y)*(va0.y+bv4.y) + (ka1.y+bk4.y)*(va1.y+bv4.y)
        + (ka2.y+bk4.y)*(va2.y+bv4.y) + (ka3.y+bk4.y)*(va3.y+bv4.y);
    p.z = (ka0.z+bk4.z)*(va0.z+bv4.z) + (ka1.z+bk4.z)*(va1.z+bv4.z)
        + (ka2.z+bk4.z)*(va2.z+bv4.z) + (ka3.z+bk4.z)*(va3.z+bv4.z);
    p.w = (ka0.w+bk4.w)*(va0.w+bv4.w) + (ka1.w+bk4.w)*(va1.w+bv4.w)
        + (ka2.w+bk4.w)*(va2.w+bv4.w) + (ka3.w+bk4.w)*(va3.w+bv4.w);
#pragma unroll
    for (int off = 1; off < 16; off <<= 1) {
        p.x += __shfl_xor(p.x, off);
        p.y += __shfl_xor(p.y, off);
        p.z += __shfl_xor(p.z, off);
        p.w += __shfl_xor(p.w, off);
    }
    if (lane == 0)
        reinterpret_cast<float4*>(partials)[(size_t)bt * 32 + cw] = p;
}

__global__ __launch_bounds__(256) void scale_kernel(
    const float* __restrict__ partials, float* __restrict__ out)
{
    __shared__ float kvs[DD];
    const int blk = blockIdx.x;          // 256 = b(4) x tt(64 tiles of 16 rows)
    const int b = blk >> 6, tt = blk & 63;
    const int tid = threadIdx.x;

    if (tid < DD) {
        float s = 0.f;
        const float* pp = partials + (size_t)b * NT * DD + tid;
#pragma unroll
        for (int j = 0; j < NT; ++j) s += pp[(size_t)j * DD];  // fixed order
        kvs[tid] = s;
    }
    __syncthreads();

    float4* o4 = reinterpret_cast<float4*>(out + ((size_t)b * NN + (size_t)tt * 16) * DD);
    const float4* kv4 = reinterpret_cast<const float4*>(kvs);
#pragma unroll
    for (int r = 0; r < 2; ++r) {
        const int idx = tid + r * 256;    // 512 float4s = 16 rows x 32
        float4 v = o4[idx];
        const float4 kk = kv4[idx & 31];
        v.x *= kk.x; v.y *= kk.y; v.z *= kk.z; v.w *= kk.w;
        o4[idx] = v;
    }
}

extern "C" void kernel_launch(void* const* d_in, const int* in_sizes, int n_in,
                              void* d_out, int out_size, void* d_ws, size_t ws_size,
                              hipStream_t stream) {
    const float* x  = (const float*)d_in[0];
    const float* Wq = (const float*)d_in[1];
    const float* bq = (const float*)d_in[2];
    const float* Wk = (const float*)d_in[3];
    const float* bk = (const float*)d_in[4];
    const float* Wv = (const float*)d_in[5];
    const float* bv = (const float*)d_in[6];
    float* out      = (float*)d_out;
    float* partials = (float*)d_ws;   // 64*32 float4s = 32 KB

    proj_kernel<<<dim3(8 * NBT), dim3(256), 0, stream>>>(
        x, Wq, bq, Wk, bk, Wv, bv, out, partials);
    scale_kernel<<<dim3(BB * (NN / 16)), dim3(256), 0, stream>>>(partials, out);
}

// Round 6
// 13.434 us; speedup vs baseline: 1.4593x; 1.4593x over previous
//
#include <hip/hip_runtime.h>

// out[b,n,d] = (x@Wq+bq)[b,n,d] * kv[b,d],  kv[b,d] = sum_m ((x@Wk+bk)*(x@Wv+bv))[b,m,d]
// B=4, N=1024, D=128, fp32 in/out.
//
// R6: MFMA bf16x3 rewrite of the proj kernel. R4/R5 proved the fp32-VALU
// formulation is DS-pipe-bound (~12cy/ds_read_b128, one pipe per CU vs 4
// SIMDs): hard ~15us floor. MFMA feeds 8192 MACs from 2 b128 frags ->
// ~10x fewer LDS instrs per FLOP, >> the 3x bf16-split expansion.
//  - split: w = hi + lo, hi = RN-bf16(w), lo = RN-bf16(w - hi); terms
//    Ah*Bh + Al*Bh + Ah*Bl (ll term ~2^-34, dropped). R2 passed with a
//    cruder split (absmax 4.0), so precision is acceptable.
//  - block 256 thr = 4 waves (2 row x 2 col subtiles of 16x16).
//    Tile: 32 rows x 32 cols. Grid 512 = cg(4, high bits) x rt(128):
//    the 4 blocks sharing an x rowtile are 128 apart -> same XCD.
//  - LDS 64KB: xh/xl[32][128] u16 (16KB) + wt[3][2][32][128] u16 (48KB,
//    [col][k] = W^T, frag-ready). 16B slices XOR-swizzled by (row&7)/(col&7)
//    so frag ds_read_b128 hits the 8-lane/quad floor. 2 blocks/CU.
//  - per wave per 32-k step: 8 ds_read_b128 + 9 mfma. Epilogue: kv from
//    C/D frags (col=lane&15, row=(lane>>4)*4+reg) + shfl_xor(16,32);
//    per-(rowgroup) partials -> ws; scale kernel (NT=64 groups) unchanged.

#define BB 4
#define NN 1024
#define DD 128

typedef __attribute__((ext_vector_type(8))) short short8;
typedef __attribute__((ext_vector_type(4))) float f32x4;

union Frag { short8 s; unsigned short h[8]; };

static __device__ __forceinline__ unsigned int bf16rn(float f) {
    const unsigned int u = __float_as_uint(f);
    return (u + 0x7FFFu + ((u >> 16) & 1u)) >> 16;   // round-to-nearest-even
}

__global__ __launch_bounds__(256, 2) void proj_kernel(
    const float* __restrict__ x,
    const float* __restrict__ Wq, const float* __restrict__ bq,
    const float* __restrict__ Wk, const float* __restrict__ bk,
    const float* __restrict__ Wv, const float* __restrict__ bv,
    float* __restrict__ qout, float* __restrict__ partials)
{
    __shared__ __align__(16) unsigned short xh[32][DD];        // 8 KB
    __shared__ __align__(16) unsigned short xl[32][DD];        // 8 KB
    __shared__ __align__(16) unsigned short wt[3][2][32][DD];  // 48 KB

    const int bid = blockIdx.x;          // 512 = cg(4) x rt(128)
    const int rt  = bid & 127;           // rows rt*32 .. rt*32+31
    const int cg  = bid >> 7;            // cols cg*32 .. cg*32+31
    const int tid = threadIdx.x;
    const int cbase = cg << 5;

    // ---- stage W^T slab as bf16 hi/lo, [col][k], swizzled 16B slices ----
    // unit: (mat, col-pair, k-quad). 1536 units, 6 per thread.
#pragma unroll
    for (int j = 0; j < 6; ++j) {
        const int u   = tid + j * 256;
        const int cp  = u & 15;              // col pair: cols 2cp, 2cp+1
        const int kq  = (u >> 4) & 31;       // k quad: k = 4kq .. 4kq+3
        const int mat = u >> 9;
        const float* wp = mat == 0 ? Wq : (mat == 1 ? Wk : Wv);
        const int c0 = cp << 1;
        float e[2][4];
#pragma unroll
        for (int i = 0; i < 4; ++i) {
            const float2 wv = *reinterpret_cast<const float2*>(
                &wp[(size_t)((kq << 2) + i) * DD + cbase + c0]);
            e[0][i] = wv.x; e[1][i] = wv.y;
        }
        const int s = kq >> 1, half = kq & 1;
        char* base = (char*)(&wt[0][0][0][0]) + (size_t)mat * (2 * 32 * DD * 2);
#pragma unroll
        for (int cc = 0; cc < 2; ++cc) {
            const int col = c0 + cc;
            unsigned long long hp = 0ull, lp = 0ull;
#pragma unroll
            for (int i = 0; i < 4; ++i) {
                const unsigned int hb = bf16rn(e[cc][i]);
                const float lo = e[cc][i] - __uint_as_float(hb << 16);
                const unsigned int lb = bf16rn(lo);
                hp |= (unsigned long long)hb << (16 * i);
                lp |= (unsigned long long)lb << (16 * i);
            }
            const int off = (((s ^ (col & 7)) << 4) + (half << 3)) + col * (DD * 2);
            *reinterpret_cast<unsigned long long*>(base + off) = hp;
            *reinterpret_cast<unsigned long long*>(base + (32 * DD * 2) + off) = lp;
        }
    }

    // ---- stage x tile as bf16 hi/lo, [row][k], swizzled 16B slices ----
    {
        const float4* src = reinterpret_cast<const float4*>(
            x + (size_t)rt * 32 * DD);
#pragma unroll
        for (int j = 0; j < 4; ++j) {
            const int idx = tid + j * 256;       // 0..1023 float4s, coalesced
            const float4 v = src[idx];
            const int row = idx >> 5, c4 = idx & 31;
            const float e[4] = {v.x, v.y, v.z, v.w};
            unsigned long long hp = 0ull, lp = 0ull;
#pragma unroll
            for (int i = 0; i < 4; ++i) {
                const unsigned int hb = bf16rn(e[i]);
                const float lo = e[i] - __uint_as_float(hb << 16);
                const unsigned int lb = bf16rn(lo);
                hp |= (unsigned long long)hb << (16 * i);
                lp |= (unsigned long long)lb << (16 * i);
            }
            const int s = c4 >> 1, half = c4 & 1;
            const int off = ((s ^ (row & 7)) << 4) + (half << 3);
            *reinterpret_cast<unsigned long long*>((char*)&xh[row][0] + off) = hp;
            *reinterpret_cast<unsigned long long*>((char*)&xl[row][0] + off) = lp;
        }
    }
    __syncthreads();

    // ---- MFMA: wave (wr,wc) computes 16x16 tiles of q,k,v ----
    const int lane  = tid & 63;
    const int w8    = tid >> 6;
    const int wr    = w8 >> 1;           // row subtile 0..1
    const int wc    = w8 & 1;            // col subtile 0..1
    const int lr    = lane & 15;
    const int kslot = lane >> 4;         // 0..3
    const int arow  = (wr << 4) + lr;    // 0..31 row in tile
    const int bcol  = (wc << 4) + lr;    // 0..31 col in slab

    f32x4 qa = {0.f, 0.f, 0.f, 0.f};
    f32x4 ka = {0.f, 0.f, 0.f, 0.f};
    f32x4 va = {0.f, 0.f, 0.f, 0.f};

    const char* xhp = (const char*)&xh[arow][0];
    const char* xlp = (const char*)&xl[arow][0];
    const int   aswz = arow & 7;
    const char* wb  = (const char*)&wt[0][0][bcol][0];   // + mat/h strides
    const int   bswz = bcol & 7;
    const int   MATS = 2 * 32 * DD * 2;  // bytes per mat
    const int   HS   = 32 * DD * 2;      // bytes per hi/lo plane

#pragma unroll
    for (int ks = 0; ks < 4; ++ks) {
        const int s   = (ks << 2) + kslot;            // 16B slice 0..15
        const int aof = (s ^ aswz) << 4;
        const int bof = (s ^ bswz) << 4;
        Frag ah, al, qh, ql, kh, kl, vh, vl;
        ah.s = *reinterpret_cast<const short8*>(xhp + aof);
        al.s = *reinterpret_cast<const short8*>(xlp + aof);
        qh.s = *reinterpret_cast<const short8*>(wb + bof);
        ql.s = *reinterpret_cast<const short8*>(wb + HS + bof);
        kh.s = *reinterpret_cast<const short8*>(wb + MATS + bof);
        kl.s = *reinterpret_cast<const short8*>(wb + MATS + HS + bof);
        vh.s = *reinterpret_cast<const short8*>(wb + 2 * MATS + bof);
        vl.s = *reinterpret_cast<const short8*>(wb + 2 * MATS + HS + bof);

        qa = __builtin_amdgcn_mfma_f32_16x16x32_bf16(ah.s, qh.s, qa, 0, 0, 0);
        qa = __builtin_amdgcn_mfma_f32_16x16x32_bf16(al.s, qh.s, qa, 0, 0, 0);
        qa = __builtin_amdgcn_mfma_f32_16x16x32_bf16(ah.s, ql.s, qa, 0, 0, 0);

        ka = __builtin_amdgcn_mfma_f32_16x16x32_bf16(ah.s, kh.s, ka, 0, 0, 0);
        ka = __builtin_amdgcn_mfma_f32_16x16x32_bf16(al.s, kh.s, ka, 0, 0, 0);
        ka = __builtin_amdgcn_mfma_f32_16x16x32_bf16(ah.s, kl.s, ka, 0, 0, 0);

        va = __builtin_amdgcn_mfma_f32_16x16x32_bf16(ah.s, vh.s, va, 0, 0, 0);
        va = __builtin_amdgcn_mfma_f32_16x16x32_bf16(al.s, vh.s, va, 0, 0, 0);
        va = __builtin_amdgcn_mfma_f32_16x16x32_bf16(ah.s, vl.s, va, 0, 0, 0);
    }

    // ---- epilogue.  C/D map: col = lane&15, row = kslot*4 + reg ----
    const int colg = cbase + (wc << 4) + lr;   // global column
    const float bqc = bq[colg], bkc = bk[colg], bvc = bv[colg];

    // q (+bias) -> out; scale kernel multiplies by kv later
    {
        const size_t rbase = ((size_t)rt * 32 + (wr << 4) + (kslot << 2)) * DD + colg;
#pragma unroll
        for (int i = 0; i < 4; ++i)
            qout[rbase + (size_t)i * DD] = qa[i] + bqc;
    }

    // kv partial for this wave's 16 rows: sum over regs, then over kslot
    float p = 0.f;
#pragma unroll
    for (int i = 0; i < 4; ++i)
        p += (ka[i] + bkc) * (va[i] + bvc);
    p += __shfl_xor(p, 16);
    p += __shfl_xor(p, 32);
    // row-group rg = rt*2 + wr (16 rows each); fixed-order reduce in kernel 2
    if (lane < 16)
        partials[(size_t)((rt << 1) + wr) * DD + colg] = p;
}

__global__ __launch_bounds__(256) void scale_kernel(
    const float* __restrict__ partials, float* __restrict__ out)
{
    __shared__ float kvs[DD];
    const int blk = blockIdx.x;          // 256 = b(4) x tt(64 slabs of 16 rows)
    const int b = blk >> 6, tt = blk & 63;
    const int tid = threadIdx.x;

    if (tid < DD) {
        float s = 0.f;
        const float* pp = partials + (size_t)b * 64 * DD + tid;
#pragma unroll
        for (int j = 0; j < 64; ++j) s += pp[(size_t)j * DD];  // fixed order
        kvs[tid] = s;
    }
    __syncthreads();

    float4* o4 = reinterpret_cast<float4*>(out + ((size_t)b * NN + (size_t)tt * 16) * DD);
    const float4* kv4 = reinterpret_cast<const float4*>(kvs);
#pragma unroll
    for (int r = 0; r < 2; ++r) {
        const int idx = tid + r * 256;    // 512 float4s = 16 rows x 32
        float4 v = o4[idx];
        const float4 kk = kv4[idx & 31];
        v.x *= kk.x; v.y *= kk.y; v.z *= kk.z; v.w *= kk.w;
        o4[idx] = v;
    }
}

extern "C" void kernel_launch(void* const* d_in, const int* in_sizes, int n_in,
                              void* d_out, int out_size, void* d_ws, size_t ws_size,
                              hipStream_t stream) {
    const float* x  = (const float*)d_in[0];
    const float* Wq = (const float*)d_in[1];
    const float* bq = (const float*)d_in[2];
    const float* Wk = (const float*)d_in[3];
    const float* bk = (const float*)d_in[4];
    const float* Wv = (const float*)d_in[5];
    const float* bv = (const float*)d_in[6];
    float* out      = (float*)d_out;
    float* partials = (float*)d_ws;   // 256 rowgroups x 128 cols = 128 KB

    proj_kernel<<<dim3(512), dim3(256), 0, stream>>>(
        x, Wq, bq, Wk, bk, Wv, bv, out, partials);
    scale_kernel<<<dim3(256), dim3(256), 0, stream>>>(partials, out);
}

// Round 7
// 12.979 us; speedup vs baseline: 1.5104x; 1.0351x over previous
//
#include <hip/hip_runtime.h>

// out[b,n,d] = (x@Wq+bq)[b,n,d] * kv[b,d],  kv[b,d] = sum_m ((x@Wk+bk)*(x@Wv+bv))[b,m,d]
// B=4, N=1024, D=128, fp32 in/out.
//
// R7 = R6 (MFMA bf16x3, 13.4us) with the staging cost cut ~4x:
//  - v_cvt_pk_bf16_f32 (HW RNE, 2 elems/instr) replaces bit-twiddled bf16rn:
//    ~3 instr/elem instead of ~11 for the hi/lo split.
//  - 64-row tiles: grid 256 = cg(4, high bits) x rt(64), 512 thr (8 waves =
//    4 row-subtiles x 2 col-subtiles of 16x16). Halves the per-block W-slab
//    conversion redundancy (64 blocks/cg instead of 128).
//  - LDS 80 KB: xh/xl[64][128] (32 KB) + wt[3][2][32][128] (48 KB).
//    1 block/CU, 2 waves/SIMD.
//  - numerics: w = hi + lo (RNE both), terms Ah*Bh + Al*Bh + Ah*Bl; identical
//    k-permutation in A and B frags (swizzled slices) cancels any pairing
//    permutation. C/D map: col=lane&15, row=(lane>>4)*4+reg (HW-verified).

#define NN 1024
#define DD 128

typedef __attribute__((ext_vector_type(8))) short short8;
typedef __attribute__((ext_vector_type(4))) float f32x4;

union Frag { short8 s; unsigned int u[4]; };

static __device__ __forceinline__ unsigned int cvtpk(float a, float b) {
    unsigned int r;
    asm("v_cvt_pk_bf16_f32 %0, %1, %2" : "=v"(r) : "v"(a), "v"(b));
    return r;   // low16 = bf16(a), high16 = bf16(b)
}

// hi-pair and lo-pair (RNE split) for elems (a,b)
static __device__ __forceinline__ void split2(float a, float b,
                                              unsigned int& hp, unsigned int& lp) {
    hp = cvtpk(a, b);
    const float ha = __uint_as_float(hp << 16);
    const float hb = __uint_as_float(hp & 0xFFFF0000u);
    lp = cvtpk(a - ha, b - hb);
}

__global__ __launch_bounds__(512, 2) void proj_kernel(
    const float* __restrict__ x,
    const float* __restrict__ Wq, const float* __restrict__ bq,
    const float* __restrict__ Wk, const float* __restrict__ bk,
    const float* __restrict__ Wv, const float* __restrict__ bv,
    float* __restrict__ qout, float* __restrict__ partials)
{
    __shared__ __align__(16) unsigned short xh[64][DD];        // 16 KB
    __shared__ __align__(16) unsigned short xl[64][DD];        // 16 KB
    __shared__ __align__(16) unsigned short wt[3][2][32][DD];  // 48 KB

    const int bid = blockIdx.x;          // 256 = cg(4) x rt(64)
    const int rt  = bid & 63;            // rows rt*64 .. rt*64+63
    const int cg  = bid >> 6;            // cols cg*32 .. cg*32+31
    const int tid = threadIdx.x;
    const int cbase = cg << 5;

    // ---- stage W slab: thread owns (col, k-octet); 8 k-elems = one 16B slice
    {
        const int col = tid & 31;
        const int ko  = (tid >> 5) & 15;             // k = 8*ko .. 8*ko+7
        const int swz = (ko ^ (col & 7)) << 4;
#pragma unroll
        for (int m = 0; m < 3; ++m) {
            const float* wp = m == 0 ? Wq : (m == 1 ? Wk : Wv);
            const float* src = wp + (size_t)(ko << 3) * DD + cbase + col;
            float e[8];
#pragma unroll
            for (int i = 0; i < 8; ++i) e[i] = src[(size_t)i * DD];  // 128B-coalesced per k-row
            unsigned int hp[4], lp[4];
#pragma unroll
            for (int j = 0; j < 4; ++j) split2(e[2*j], e[2*j+1], hp[j], lp[j]);
            *reinterpret_cast<int4*>((char*)&wt[m][0][col][0] + swz) =
                *reinterpret_cast<int4*>(hp);
            *reinterpret_cast<int4*>((char*)&wt[m][1][col][0] + swz) =
                *reinterpret_cast<int4*>(lp);
        }
    }

    // ---- stage x tile [64 rows][128 k] as hi/lo planes, swizzled slices ----
    {
        const float4* src = reinterpret_cast<const float4*>(x + (size_t)rt * 64 * DD);
#pragma unroll
        for (int j = 0; j < 4; ++j) {
            const int idx = tid + j * 512;           // 0..2047 float4s, coalesced
            const float4 v = src[idx];
            const int row = idx >> 5, c4 = idx & 31;
            const int s = c4 >> 1, half = c4 & 1;
            const int off = ((s ^ (row & 7)) << 4) + (half << 3);
            unsigned int h0, l0, h1, l1;
            split2(v.x, v.y, h0, l0);
            split2(v.z, v.w, h1, l1);
            const unsigned long long hp =
                (unsigned long long)h0 | ((unsigned long long)h1 << 32);
            const unsigned long long lp =
                (unsigned long long)l0 | ((unsigned long long)l1 << 32);
            *reinterpret_cast<unsigned long long*>((char*)&xh[row][0] + off) = hp;
            *reinterpret_cast<unsigned long long*>((char*)&xl[row][0] + off) = lp;
        }
    }
    __syncthreads();

    // ---- MFMA: wave (wr 0..3, wc 0..1) -> one 16x16 tile of q,k,v ----
    const int lane  = tid & 63;
    const int w8    = tid >> 6;
    const int wr    = w8 >> 1;
    const int wc    = w8 & 1;
    const int lr    = lane & 15;
    const int kslot = lane >> 4;
    const int arow  = (wr << 4) + lr;     // 0..63
    const int bcol  = (wc << 4) + lr;     // 0..31

    f32x4 qa = {0.f, 0.f, 0.f, 0.f};
    f32x4 ka = {0.f, 0.f, 0.f, 0.f};
    f32x4 va = {0.f, 0.f, 0.f, 0.f};

    const char* xhp = (const char*)&xh[arow][0];
    const char* xlp = (const char*)&xl[arow][0];
    const int   aswz = arow & 7;
    const char* wb   = (const char*)&wt[0][0][bcol][0];
    const int   bswz = bcol & 7;
    const int   MATS = 2 * 32 * DD * 2;   // bytes per mat
    const int   HS   = 32 * DD * 2;       // bytes per hi/lo plane

#pragma unroll
    for (int ks = 0; ks < 4; ++ks) {
        const int s   = (ks << 2) + kslot;            // 16B slice 0..15
        const int aof = (s ^ aswz) << 4;
        const int bof = (s ^ bswz) << 4;
        Frag ah, al, qh, ql, kh, kl, vh, vl;
        ah.s = *reinterpret_cast<const short8*>(xhp + aof);
        al.s = *reinterpret_cast<const short8*>(xlp + aof);
        qh.s = *reinterpret_cast<const short8*>(wb + bof);
        ql.s = *reinterpret_cast<const short8*>(wb + HS + bof);
        kh.s = *reinterpret_cast<const short8*>(wb + MATS + bof);
        kl.s = *reinterpret_cast<const short8*>(wb + MATS + HS + bof);
        vh.s = *reinterpret_cast<const short8*>(wb + 2 * MATS + bof);
        vl.s = *reinterpret_cast<const short8*>(wb + 2 * MATS + HS + bof);

        qa = __builtin_amdgcn_mfma_f32_16x16x32_bf16(ah.s, qh.s, qa, 0, 0, 0);
        qa = __builtin_amdgcn_mfma_f32_16x16x32_bf16(al.s, qh.s, qa, 0, 0, 0);
        qa = __builtin_amdgcn_mfma_f32_16x16x32_bf16(ah.s, ql.s, qa, 0, 0, 0);

        ka = __builtin_amdgcn_mfma_f32_16x16x32_bf16(ah.s, kh.s, ka, 0, 0, 0);
        ka = __builtin_amdgcn_mfma_f32_16x16x32_bf16(al.s, kh.s, ka, 0, 0, 0);
        ka = __builtin_amdgcn_mfma_f32_16x16x32_bf16(ah.s, kl.s, ka, 0, 0, 0);

        va = __builtin_amdgcn_mfma_f32_16x16x32_bf16(ah.s, vh.s, va, 0, 0, 0);
        va = __builtin_amdgcn_mfma_f32_16x16x32_bf16(al.s, vh.s, va, 0, 0, 0);
        va = __builtin_amdgcn_mfma_f32_16x16x32_bf16(ah.s, vl.s, va, 0, 0, 0);
    }

    // ---- epilogue.  C/D map: col = lane&15, row = kslot*4 + reg ----
    const int colg = cbase + (wc << 4) + lr;
    const float bqc = bq[colg], bkc = bk[colg], bvc = bv[colg];

    {
        const size_t rbase =
            ((size_t)rt * 64 + (wr << 4) + (kslot << 2)) * DD + colg;
#pragma unroll
        for (int i = 0; i < 4; ++i)
            qout[rbase + (size_t)i * DD] = qa[i] + bqc;
    }

    float p = 0.f;
#pragma unroll
    for (int i = 0; i < 4; ++i)
        p += (ka[i] + bkc) * (va[i] + bvc);
    p += __shfl_xor(p, 16);
    p += __shfl_xor(p, 32);
    // rowgroup rg = rt*4 + wr (16 rows each); 64 groups per batch
    if (lane < 16)
        partials[(size_t)((rt << 2) + wr) * DD + colg] = p;
}

__global__ __launch_bounds__(256) void scale_kernel(
    const float* __restrict__ partials, float* __restrict__ out)
{
    __shared__ float kvs[DD];
    const int blk = blockIdx.x;          // 256 = b(4) x tt(64 slabs of 16 rows)
    const int b = blk >> 6, tt = blk & 63;
    const int tid = threadIdx.x;

    if (tid < DD) {
        float s = 0.f;
        const float* pp = partials + (size_t)b * 64 * DD + tid;
#pragma unroll
        for (int j = 0; j < 64; ++j) s += pp[(size_t)j * DD];  // fixed order
        kvs[tid] = s;
    }
    __syncthreads();

    float4* o4 = reinterpret_cast<float4*>(out + ((size_t)b * NN + (size_t)tt * 16) * DD);
    const float4* kv4 = reinterpret_cast<const float4*>(kvs);
#pragma unroll
    for (int r = 0; r < 2; ++r) {
        const int idx = tid + r * 256;    // 512 float4s = 16 rows x 32
        float4 v = o4[idx];
        const float4 kk = kv4[idx & 31];
        v.x *= kk.x; v.y *= kk.y; v.z *= kk.z; v.w *= kk.w;
        o4[idx] = v;
    }
}

extern "C" void kernel_launch(void* const* d_in, const int* in_sizes, int n_in,
                              void* d_out, int out_size, void* d_ws, size_t ws_size,
                              hipStream_t stream) {
    const float* x  = (const float*)d_in[0];
    const float* Wq = (const float*)d_in[1];
    const float* bq = (const float*)d_in[2];
    const float* Wk = (const float*)d_in[3];
    const float* bk = (const float*)d_in[4];
    const float* Wv = (const float*)d_in[5];
    const float* bv = (const float*)d_in[6];
    float* out      = (float*)d_out;
    float* partials = (float*)d_ws;   // 256 rowgroups x 128 cols = 128 KB

    proj_kernel<<<dim3(256), dim3(512), 0, stream>>>(
        x, Wq, bq, Wk, bk, Wv, bv, out, partials);
    scale_kernel<<<dim3(256), dim3(256), 0, stream>>>(partials, out);
}